// Round 2
// baseline (2921.221 us; speedup 1.0000x reference)
//
#include <hip/hip_runtime.h>
#include <hip/hip_bf16.h>
#include <math.h>

#define NNODES 50000
#define NEDGES 800000
#define DIM 128

// ---------------------------------------------------------------------------
// C[M,N] = A[M,128] @ B[N,128]^T + bias[N]
// Tiles: BM=BN=64, BK=32, 256 threads, 4x4 microtile per thread.
// LDS pad to 68 floats/row: keeps ds_read 16B-aligned (68*4 % 16 == 0),
// read conflicts are 2-way (free on CDNA4).
// ---------------------------------------------------------------------------
__global__ __launch_bounds__(256)
void gemm_nt_bias(const float* __restrict__ A, const float* __restrict__ B,
                  const float* __restrict__ bias, float* __restrict__ C,
                  int M, int N) {
    __shared__ float As[32][68];
    __shared__ float Bs[32][68];
    const int tid = threadIdx.x;
    const int bm = blockIdx.x * 64;
    const int bn = blockIdx.y * 64;
    const int tx = tid & 15;   // -> n
    const int ty = tid >> 4;   // -> m
    const int lr = tid >> 3;        // 0..31 row for staging
    const int lc = (tid & 7) << 2;  // 0..28 k-col for staging

    float acc[4][4] = {};

    for (int k0 = 0; k0 < DIM; k0 += 32) {
        #pragma unroll
        for (int p = 0; p < 2; ++p) {
            const int row = lr + p * 32;
            const int ga = bm + row;
            float4 va = make_float4(0.f, 0.f, 0.f, 0.f);
            if (ga < M) va = *(const float4*)(A + (size_t)ga * DIM + k0 + lc);
            As[lc + 0][row] = va.x; As[lc + 1][row] = va.y;
            As[lc + 2][row] = va.z; As[lc + 3][row] = va.w;
            const int gb = bn + row;
            float4 vb = make_float4(0.f, 0.f, 0.f, 0.f);
            if (gb < N) vb = *(const float4*)(B + (size_t)gb * DIM + k0 + lc);
            Bs[lc + 0][row] = vb.x; Bs[lc + 1][row] = vb.y;
            Bs[lc + 2][row] = vb.z; Bs[lc + 3][row] = vb.w;
        }
        __syncthreads();
        #pragma unroll
        for (int kk = 0; kk < 32; ++kk) {
            float a0 = As[kk][ty * 4 + 0];
            float a1 = As[kk][ty * 4 + 1];
            float a2 = As[kk][ty * 4 + 2];
            float a3 = As[kk][ty * 4 + 3];
            float b0 = Bs[kk][tx * 4 + 0];
            float b1 = Bs[kk][tx * 4 + 1];
            float b2 = Bs[kk][tx * 4 + 2];
            float b3 = Bs[kk][tx * 4 + 3];
            acc[0][0] += a0 * b0; acc[0][1] += a0 * b1; acc[0][2] += a0 * b2; acc[0][3] += a0 * b3;
            acc[1][0] += a1 * b0; acc[1][1] += a1 * b1; acc[1][2] += a1 * b2; acc[1][3] += a1 * b3;
            acc[2][0] += a2 * b0; acc[2][1] += a2 * b1; acc[2][2] += a2 * b2; acc[2][3] += a2 * b3;
            acc[3][0] += a3 * b0; acc[3][1] += a3 * b1; acc[3][2] += a3 * b2; acc[3][3] += a3 * b3;
        }
        __syncthreads();
    }

    #pragma unroll
    for (int i = 0; i < 4; ++i) {
        const int row = bm + ty * 4 + i;
        if (row >= M) continue;
        #pragma unroll
        for (int j = 0; j < 4; ++j) {
            const int col = bn + tx * 4 + j;
            if (col < N) C[(size_t)row * N + col] = acc[i][j] + bias[col];
        }
    }
}

// ---------------------------------------------------------------------------
// a[dst[e]] += Y[src[e], etype[e]*128 .. +128]   (bias already folded into Y)
// One 64-lane wave per edge; float2 per lane; fp32 atomics.
// ---------------------------------------------------------------------------
__global__ __launch_bounds__(256)
void edge_scatter(const float* __restrict__ Y, const int* __restrict__ src,
                  const int* __restrict__ dst, const int* __restrict__ et,
                  float* __restrict__ a) {
    const int wid = (blockIdx.x << 2) + (threadIdx.x >> 6);
    const int lane = threadIdx.x & 63;
    if (wid >= NEDGES) return;
    const int s = src[wid];
    const int d = dst[wid];
    const int t = et[wid];
    const float2 v = *(const float2*)(Y + (size_t)s * 512 + t * DIM + lane * 2);
    float* ap = a + (size_t)d * DIM + lane * 2;
    atomicAdd(ap + 0, v.x);
    atomicAdd(ap + 1, v.y);
}

// ---------------------------------------------------------------------------
// GRU gates: h' = (1-z)*n + z*h ; r=sig(ir+hr), z=sig(iz+hz), n=tanh(in+r*hn)
// One thread per 4 output elems (float4).
// ---------------------------------------------------------------------------
__device__ __forceinline__ float sigf(float x) { return 1.f / (1.f + expf(-x)); }

__global__ __launch_bounds__(256)
void gru_gate(const float* __restrict__ gi, const float* __restrict__ gh,
              const float* __restrict__ h_in, float* __restrict__ h_out) {
    const int idx = blockIdx.x * 256 + threadIdx.x;
    const int v = idx >> 5;          // 32 quads per node
    const int q = (idx & 31) << 2;
    if (v >= NNODES) return;
    const size_t gbase = (size_t)v * 384 + q;
    const float4 ir = *(const float4*)(gi + gbase);
    const float4 iz = *(const float4*)(gi + gbase + 128);
    const float4 in4 = *(const float4*)(gi + gbase + 256);
    const float4 hr = *(const float4*)(gh + gbase);
    const float4 hz = *(const float4*)(gh + gbase + 128);
    const float4 hn = *(const float4*)(gh + gbase + 256);
    const float4 h4 = *(const float4*)(h_in + (size_t)v * DIM + q);
    float4 o;
    {
        const float r = sigf(ir.x + hr.x);
        const float z = sigf(iz.x + hz.x);
        const float n = tanhf(in4.x + r * hn.x);
        o.x = (1.f - z) * n + z * h4.x;
    }
    {
        const float r = sigf(ir.y + hr.y);
        const float z = sigf(iz.y + hz.y);
        const float n = tanhf(in4.y + r * hn.y);
        o.y = (1.f - z) * n + z * h4.y;
    }
    {
        const float r = sigf(ir.z + hr.z);
        const float z = sigf(iz.z + hz.z);
        const float n = tanhf(in4.z + r * hn.z);
        o.z = (1.f - z) * n + z * h4.z;
    }
    {
        const float r = sigf(ir.w + hr.w);
        const float z = sigf(iz.w + hz.w);
        const float n = tanhf(in4.w + r * hn.w);
        o.w = (1.f - z) * n + z * h4.w;
    }
    *(float4*)(h_out + (size_t)v * DIM + q) = o;
}

// ---------------------------------------------------------------------------
extern "C" void kernel_launch(void* const* d_in, const int* in_sizes, int n_in,
                              void* d_out, int out_size, void* d_ws, size_t ws_size,
                              hipStream_t stream) {
    const float* feat  = (const float*)d_in[0];
    const float* W_lin = (const float*)d_in[1];   // [4,128,128] == [512,128]
    const float* b_lin = (const float*)d_in[2];   // [512]
    const float* w_ih  = (const float*)d_in[3];   // [384,128]
    const float* w_hh  = (const float*)d_in[4];   // [384,128]
    const float* b_ih  = (const float*)d_in[5];   // [384]
    const float* b_hh  = (const float*)d_in[6];   // [384]
    const int*   src   = (const int*)d_in[7];
    const int*   dst   = (const int*)d_in[8];
    const int*   et    = (const int*)d_in[9];
    float* out = (float*)d_out;

    // ws layout (floats), with deliberate dead-buffer reuse:
    //   h  : [0, 6.4M)
    //   Y  : [6.4M, 32M)          (50000*512)
    //   a  : [32M, 38.4M)
    //   gi : = Y base  [6.4M, 25.6M)      (Y dead after edge_scatter)
    //   gh : [25.6M, 44.8M)               (overlaps Y-tail + a; both dead then)
    // total 44.8M floats = 179.2 MB
    float* h  = (float*)d_ws;
    float* Y  = h + (size_t)NNODES * DIM;
    float* a  = Y + (size_t)NNODES * 512;
    float* gi = Y;
    float* gh = gi + (size_t)NNODES * 384;

    const dim3 blk(256);
    const int mblocks = (NNODES + 63) / 64;   // 782

    for (int s = 0; s < 3; ++s) {
        const float* h_in = (s == 0) ? feat : h;
        float* h_out = (s == 2) ? out : h;

        // Y = h_in @ W_lin^T + b_lin   [50000, 512]
        gemm_nt_bias<<<dim3(mblocks, 8), blk, 0, stream>>>(h_in, W_lin, b_lin, Y, NNODES, 512);
        // a = 0
        hipMemsetAsync(a, 0, (size_t)NNODES * DIM * sizeof(float), stream);
        // a[dst] += Y[src, et*128..]
        edge_scatter<<<dim3(NEDGES / 4), blk, 0, stream>>>(Y, src, dst, et, a);
        // gi = a @ w_ih^T + b_ih   [50000, 384]
        gemm_nt_bias<<<dim3(mblocks, 6), blk, 0, stream>>>(a, w_ih, b_ih, gi, NNODES, 384);
        // gh = h_in @ w_hh^T + b_hh [50000, 384]
        gemm_nt_bias<<<dim3(mblocks, 6), blk, 0, stream>>>(h_in, w_hh, b_hh, gh, NNODES, 384);
        // gates
        gru_gate<<<dim3((NNODES * 32 + 255) / 256), blk, 0, stream>>>(gi, gh, h_in, h_out);
    }
}

// Round 3
// 1394.382 us; speedup vs baseline: 2.0950x; 2.0950x over previous
//
#include <hip/hip_runtime.h>
#include <hip/hip_bf16.h>
#include <math.h>

#define NNODES 50000
#define NEDGES 800000
#define DIM 128

// ---------------------------------------------------------------------------
// C[M,N] = A[M,128] @ B[N,128]^T + bias[N]
// Tiles: BM=BN=64, BK=32, 256 threads, 4x4 microtile per thread.
// ---------------------------------------------------------------------------
__global__ __launch_bounds__(256)
void gemm_nt_bias(const float* __restrict__ A, const float* __restrict__ B,
                  const float* __restrict__ bias, float* __restrict__ C,
                  int M, int N) {
    __shared__ float As[32][68];
    __shared__ float Bs[32][68];
    const int tid = threadIdx.x;
    const int bm = blockIdx.x * 64;
    const int bn = blockIdx.y * 64;
    const int tx = tid & 15;   // -> n
    const int ty = tid >> 4;   // -> m
    const int lr = tid >> 3;        // 0..31 row for staging
    const int lc = (tid & 7) << 2;  // 0..28 k-col for staging

    float acc[4][4] = {};

    for (int k0 = 0; k0 < DIM; k0 += 32) {
        #pragma unroll
        for (int p = 0; p < 2; ++p) {
            const int row = lr + p * 32;
            const int ga = bm + row;
            float4 va = make_float4(0.f, 0.f, 0.f, 0.f);
            if (ga < M) va = *(const float4*)(A + (size_t)ga * DIM + k0 + lc);
            As[lc + 0][row] = va.x; As[lc + 1][row] = va.y;
            As[lc + 2][row] = va.z; As[lc + 3][row] = va.w;
            const int gb = bn + row;
            float4 vb = make_float4(0.f, 0.f, 0.f, 0.f);
            if (gb < N) vb = *(const float4*)(B + (size_t)gb * DIM + k0 + lc);
            Bs[lc + 0][row] = vb.x; Bs[lc + 1][row] = vb.y;
            Bs[lc + 2][row] = vb.z; Bs[lc + 3][row] = vb.w;
        }
        __syncthreads();
        #pragma unroll
        for (int kk = 0; kk < 32; ++kk) {
            float a0 = As[kk][ty * 4 + 0];
            float a1 = As[kk][ty * 4 + 1];
            float a2 = As[kk][ty * 4 + 2];
            float a3 = As[kk][ty * 4 + 3];
            float b0 = Bs[kk][tx * 4 + 0];
            float b1 = Bs[kk][tx * 4 + 1];
            float b2 = Bs[kk][tx * 4 + 2];
            float b3 = Bs[kk][tx * 4 + 3];
            acc[0][0] += a0 * b0; acc[0][1] += a0 * b1; acc[0][2] += a0 * b2; acc[0][3] += a0 * b3;
            acc[1][0] += a1 * b0; acc[1][1] += a1 * b1; acc[1][2] += a1 * b2; acc[1][3] += a1 * b3;
            acc[2][0] += a2 * b0; acc[2][1] += a2 * b1; acc[2][2] += a2 * b2; acc[2][3] += a2 * b3;
            acc[3][0] += a3 * b0; acc[3][1] += a3 * b1; acc[3][2] += a3 * b2; acc[3][3] += a3 * b3;
        }
        __syncthreads();
    }

    #pragma unroll
    for (int i = 0; i < 4; ++i) {
        const int row = bm + ty * 4 + i;
        if (row >= M) continue;
        #pragma unroll
        for (int j = 0; j < 4; ++j) {
            const int col = bn + tx * 4 + j;
            if (col < N) C[(size_t)row * N + col] = acc[i][j] + bias[col];
        }
    }
}

// ---------------------------------------------------------------------------
// CSR-by-dst construction (once per call; topology fixed across 3 steps).
// ---------------------------------------------------------------------------
__global__ __launch_bounds__(256)
void hist_dst(const int* __restrict__ dst, int* __restrict__ cnt) {
    const int e = blockIdx.x * 256 + threadIdx.x;
    if (e < NEDGES) atomicAdd(&cnt[dst[e]], 1);
}

// single-block exclusive scan over cnt[0..NNODES) -> row_start[0..NNODES]
__global__ __launch_bounds__(1024)
void scan_counts(const int* __restrict__ cnt, int* __restrict__ row_start) {
    __shared__ int psum[1024];
    const int t = threadIdx.x;
    const int CH = (NNODES + 1023) / 1024;   // 49
    const int base = t * CH;
    int s = 0;
    for (int i = 0; i < CH; ++i) {
        const int idx = base + i;
        if (idx < NNODES) s += cnt[idx];
    }
    psum[t] = s;
    __syncthreads();
    // Hillis-Steele inclusive scan over 1024 partials
    for (int off = 1; off < 1024; off <<= 1) {
        int v = (t >= off) ? psum[t - off] : 0;
        __syncthreads();
        psum[t] += v;
        __syncthreads();
    }
    int run = (t == 0) ? 0 : psum[t - 1];
    for (int i = 0; i < CH; ++i) {
        const int idx = base + i;
        if (idx < NNODES) {
            row_start[idx] = run;
            run += cnt[idx];
        }
    }
    if (t == 1023) row_start[NNODES] = psum[1023];
}

// perm[pos] = src | (etype<<16), pos via per-dst cursor
__global__ __launch_bounds__(256)
void scatter_edges(const int* __restrict__ src, const int* __restrict__ dst,
                   const int* __restrict__ et, int* __restrict__ cursor,
                   int* __restrict__ perm) {
    const int e = blockIdx.x * 256 + threadIdx.x;
    if (e >= NEDGES) return;
    const int d = dst[e];
    const int pos = atomicAdd(&cursor[d], 1);
    perm[pos] = src[e] | (et[e] << 16);
}

// ---------------------------------------------------------------------------
// a[v] = sum over incoming edges of Y[src, et*128..]  — one wave per node,
// register accumulation, single coalesced write. No atomics.
// ---------------------------------------------------------------------------
__global__ __launch_bounds__(256)
void edge_agg(const float* __restrict__ Y, const int* __restrict__ perm,
              const int* __restrict__ row_start, float* __restrict__ a) {
    const int node = blockIdx.x * 4 + (threadIdx.x >> 6);
    const int lane = threadIdx.x & 63;
    if (node >= NNODES) return;
    const int beg = row_start[node];
    const int end = row_start[node + 1];
    float2 acc = make_float2(0.f, 0.f);
    for (int i = beg; i < end; ++i) {
        const int p = perm[i];                    // wave-uniform
        const int s = p & 0xFFFF;
        const int t = p >> 16;
        const float2 v = *(const float2*)(Y + (size_t)s * 512 + t * DIM + lane * 2);
        acc.x += v.x;
        acc.y += v.y;
    }
    *(float2*)(a + (size_t)node * DIM + lane * 2) = acc;
}

// ---------------------------------------------------------------------------
// GRU gates: h' = (1-z)*n + z*h
// ---------------------------------------------------------------------------
__device__ __forceinline__ float sigf(float x) { return 1.f / (1.f + expf(-x)); }

__global__ __launch_bounds__(256)
void gru_gate(const float* __restrict__ gi, const float* __restrict__ gh,
              const float* __restrict__ h_in, float* __restrict__ h_out) {
    const int idx = blockIdx.x * 256 + threadIdx.x;
    const int v = idx >> 5;          // 32 quads per node
    const int q = (idx & 31) << 2;
    if (v >= NNODES) return;
    const size_t gbase = (size_t)v * 384 + q;
    const float4 ir = *(const float4*)(gi + gbase);
    const float4 iz = *(const float4*)(gi + gbase + 128);
    const float4 in4 = *(const float4*)(gi + gbase + 256);
    const float4 hr = *(const float4*)(gh + gbase);
    const float4 hz = *(const float4*)(gh + gbase + 128);
    const float4 hn = *(const float4*)(gh + gbase + 256);
    const float4 h4 = *(const float4*)(h_in + (size_t)v * DIM + q);
    float4 o;
    {
        const float r = sigf(ir.x + hr.x);
        const float z = sigf(iz.x + hz.x);
        const float n = tanhf(in4.x + r * hn.x);
        o.x = (1.f - z) * n + z * h4.x;
    }
    {
        const float r = sigf(ir.y + hr.y);
        const float z = sigf(iz.y + hz.y);
        const float n = tanhf(in4.y + r * hn.y);
        o.y = (1.f - z) * n + z * h4.y;
    }
    {
        const float r = sigf(ir.z + hr.z);
        const float z = sigf(iz.z + hz.z);
        const float n = tanhf(in4.z + r * hn.z);
        o.z = (1.f - z) * n + z * h4.z;
    }
    {
        const float r = sigf(ir.w + hr.w);
        const float z = sigf(iz.w + hz.w);
        const float n = tanhf(in4.w + r * hn.w);
        o.w = (1.f - z) * n + z * h4.w;
    }
    *(float4*)(h_out + (size_t)v * DIM + q) = o;
}

// ---------------------------------------------------------------------------
extern "C" void kernel_launch(void* const* d_in, const int* in_sizes, int n_in,
                              void* d_out, int out_size, void* d_ws, size_t ws_size,
                              hipStream_t stream) {
    const float* feat  = (const float*)d_in[0];
    const float* W_lin = (const float*)d_in[1];   // [4,128,128] == [512,128]
    const float* b_lin = (const float*)d_in[2];   // [512]
    const float* w_ih  = (const float*)d_in[3];   // [384,128]
    const float* w_hh  = (const float*)d_in[4];   // [384,128]
    const float* b_ih  = (const float*)d_in[5];   // [384]
    const float* b_hh  = (const float*)d_in[6];   // [384]
    const int*   src   = (const int*)d_in[7];
    const int*   dst   = (const int*)d_in[8];
    const int*   et    = (const int*)d_in[9];
    float* out = (float*)d_out;

    // ws layout (floats):
    //   h  : [0, 6.4M)
    //   Y  : [6.4M, 32M)          (50000*512)
    //   a  : [32M, 38.4M)
    //   gi : = Y base  [6.4M, 25.6M)   (Y dead after edge_agg)
    //   gh : [25.6M, 44.8M)            (overlaps Y-tail + a; both dead by then)
    //   ints after 44.8M floats: row_start[50001], perm[800000]
    //   cursor overlaps `a` region (a is dead during CSR build at call start)
    float* h  = (float*)d_ws;
    float* Y  = h + (size_t)NNODES * DIM;
    float* a  = Y + (size_t)NNODES * 512;
    float* gi = Y;
    float* gh = gi + (size_t)NNODES * 384;
    int* row_start = (int*)(gh + (size_t)NNODES * 384);  // 44.8M floats in
    int* perm      = row_start + (NNODES + 1);
    int* cnt       = (int*)a;            // transient, dead before edge_agg
    int* cursor    = cnt + NNODES + 64;  // transient

    const dim3 blk(256);
    const int mblocks = (NNODES + 63) / 64;   // 782
    const int eblocks = (NEDGES + 255) / 256; // 3125

    // ---- build dst-CSR once (topology constant across steps) ----
    hipMemsetAsync(cnt, 0, (size_t)NNODES * sizeof(int), stream);
    hist_dst<<<dim3(eblocks), blk, 0, stream>>>(dst, cnt);
    scan_counts<<<dim3(1), dim3(1024), 0, stream>>>(cnt, row_start);
    hipMemcpyAsync(cursor, row_start, (size_t)NNODES * sizeof(int),
                   hipMemcpyDeviceToDevice, stream);
    scatter_edges<<<dim3(eblocks), blk, 0, stream>>>(src, dst, et, cursor, perm);

    for (int s = 0; s < 3; ++s) {
        const float* h_in = (s == 0) ? feat : h;
        float* h_out = (s == 2) ? out : h;

        // Y = h_in @ W_lin^T + b_lin   [50000, 512]
        gemm_nt_bias<<<dim3(mblocks, 8), blk, 0, stream>>>(h_in, W_lin, b_lin, Y, NNODES, 512);
        // a[v] = sum_{e: dst=v} Y[src_e, et_e*128..]
        edge_agg<<<dim3((NNODES + 3) / 4), blk, 0, stream>>>(Y, perm, row_start, a);
        // gi = a @ w_ih^T + b_ih   [50000, 384]
        gemm_nt_bias<<<dim3(mblocks, 6), blk, 0, stream>>>(a, w_ih, b_ih, gi, NNODES, 384);
        // gh = h_in @ w_hh^T + b_hh [50000, 384]
        gemm_nt_bias<<<dim3(mblocks, 6), blk, 0, stream>>>(h_in, w_hh, b_hh, gh, NNODES, 384);
        // gates
        gru_gate<<<dim3((NNODES * 32 + 255) / 256), blk, 0, stream>>>(gi, gh, h_in, h_out);
    }
}

// Round 7
// 967.929 us; speedup vs baseline: 3.0180x; 1.4406x over previous
//
#include <hip/hip_runtime.h>
#include <hip/hip_bf16.h>
#include <math.h>

#define NNODES 50000
#define NEDGES 800000
#define DIM 128

typedef __attribute__((ext_vector_type(8))) short bf16x8;
typedef __attribute__((ext_vector_type(4))) float f32x4;

// fp32 -> bf16 with round-to-nearest-even (2 VALU ops)
__device__ __forceinline__ short f2bf(float f) {
    unsigned int u = __float_as_uint(f);
    u += 0x7FFFu + ((u >> 16) & 1u);
    return (short)(u >> 16);
}

// ---------------------------------------------------------------------------
// C[M,N] = A[M,128] @ B[N,128]^T + bias[N], bf16 MFMA, fp32 accum.
// BM=BN=128, K=128 staged whole (no K loop). 256 threads = 4 waves (2x2),
// each wave owns a 64x64 output tile = 4x4 fragments of 16x16.
// LDS is FRAGMENT-LINEAR: 16B unit u = (frag16*4 + ks)*64 + lane, so both
// staging writes (tid*16 linear) and fragment reads (lane*16 linear) are
// bank-conflict-free by construction.
//   A unit u: mi=u>>8, ks=(u>>6)&3, lane=u&63, r=lane&15, kslot=lane>>4
//             holds A[mi*16+r][ks*32+kslot*8 .. +8) as 8 bf16.
// ---------------------------------------------------------------------------
__global__ __launch_bounds__(256, 2)
void gemm_mfma_bias(const float* __restrict__ A, const float* __restrict__ B,
                    const float* __restrict__ bias, float* __restrict__ C,
                    int M, int N) {
    __shared__ short lsA[128 * 128];   // 32 KB
    __shared__ short lsB[128 * 128];   // 32 KB
    const int t = threadIdx.x;
    const int bm = blockIdx.x * 128;
    const int bn = blockIdx.y * 128;

    // ---- stage A and B tiles (fp32 -> bf16), linear LDS writes ----
    #pragma unroll
    for (int i = 0; i < 8; ++i) {
        const int u = i * 256 + t;
        const int fi = u >> 8;          // mi (A) / ni (B)
        const int ks = (u >> 6) & 3;
        const int ln = u & 63;
        const int r = ln & 15;
        const int gk = ks * 32 + (ln >> 4) * 8;

        // A: guard M tail
        const int grow = bm + fi * 16 + r;
        bf16x8 va = {0, 0, 0, 0, 0, 0, 0, 0};
        if (grow < M) {
            const float4 f0 = *(const float4*)(A + (size_t)grow * DIM + gk);
            const float4 f1 = *(const float4*)(A + (size_t)grow * DIM + gk + 4);
            va[0] = f2bf(f0.x); va[1] = f2bf(f0.y); va[2] = f2bf(f0.z); va[3] = f2bf(f0.w);
            va[4] = f2bf(f1.x); va[5] = f2bf(f1.y); va[6] = f2bf(f1.z); va[7] = f2bf(f1.w);
        }
        *(bf16x8*)(lsA + (size_t)u * 8) = va;

        // B: N % 128 == 0, no guard
        const int gcol = bn + fi * 16 + r;
        const float4 g0 = *(const float4*)(B + (size_t)gcol * DIM + gk);
        const float4 g1 = *(const float4*)(B + (size_t)gcol * DIM + gk + 4);
        bf16x8 vb;
        vb[0] = f2bf(g0.x); vb[1] = f2bf(g0.y); vb[2] = f2bf(g0.z); vb[3] = f2bf(g0.w);
        vb[4] = f2bf(g1.x); vb[5] = f2bf(g1.y); vb[6] = f2bf(g1.z); vb[7] = f2bf(g1.w);
        *(bf16x8*)(lsB + (size_t)u * 8) = vb;
    }
    __syncthreads();

    // ---- compute ----
    const int lane = t & 63;
    const int wave = t >> 6;
    const int wm = wave >> 1;   // 0..1
    const int wn = wave & 1;    // 0..1

    f32x4 acc[4][4];
    #pragma unroll
    for (int mi = 0; mi < 4; ++mi)
        #pragma unroll
        for (int nj = 0; nj < 4; ++nj)
            acc[mi][nj] = (f32x4){0.f, 0.f, 0.f, 0.f};

    #pragma unroll
    for (int ks = 0; ks < 4; ++ks) {
        bf16x8 af[4], bfr[4];
        #pragma unroll
        for (int mi = 0; mi < 4; ++mi)
            af[mi] = *(const bf16x8*)(lsA + (size_t)((((wm * 4 + mi) * 4 + ks) * 64 + lane)) * 8);
        #pragma unroll
        for (int nj = 0; nj < 4; ++nj)
            bfr[nj] = *(const bf16x8*)(lsB + (size_t)((((wn * 4 + nj) * 4 + ks) * 64 + lane)) * 8);
        #pragma unroll
        for (int mi = 0; mi < 4; ++mi)
            #pragma unroll
            for (int nj = 0; nj < 4; ++nj)
                acc[mi][nj] = __builtin_amdgcn_mfma_f32_16x16x32_bf16(
                    af[mi], bfr[nj], acc[mi][nj], 0, 0, 0);
    }

    // ---- epilogue: C/D map col=lane&15, row=(lane>>4)*4+reg ----
    const int cr = lane >> 4;
    const int cc = lane & 15;
    float bv[4];
    #pragma unroll
    for (int nj = 0; nj < 4; ++nj)
        bv[nj] = bias[bn + wn * 64 + nj * 16 + cc];

    #pragma unroll
    for (int mi = 0; mi < 4; ++mi) {
        const int row0 = bm + wm * 64 + mi * 16 + cr * 4;
        #pragma unroll
        for (int reg = 0; reg < 4; ++reg) {
            const int row = row0 + reg;
            if (row >= M) continue;
            #pragma unroll
            for (int nj = 0; nj < 4; ++nj) {
                const int col = bn + wn * 64 + nj * 16 + cc;
                C[(size_t)row * N + col] = acc[mi][nj][reg] + bv[nj];
            }
        }
    }
}

// ---------------------------------------------------------------------------
// CSR-by-dst construction (once per call; topology fixed across 3 steps).
// ---------------------------------------------------------------------------
__global__ __launch_bounds__(256)
void hist_dst(const int* __restrict__ dst, int* __restrict__ cnt) {
    const int e = blockIdx.x * 256 + threadIdx.x;
    if (e < NEDGES) atomicAdd(&cnt[dst[e]], 1);
}

__global__ __launch_bounds__(1024)
void scan_counts(const int* __restrict__ cnt, int* __restrict__ row_start) {
    __shared__ int psum[1024];
    const int t = threadIdx.x;
    const int CH = (NNODES + 1023) / 1024;   // 49
    const int base = t * CH;
    int s = 0;
    for (int i = 0; i < CH; ++i) {
        const int idx = base + i;
        if (idx < NNODES) s += cnt[idx];
    }
    psum[t] = s;
    __syncthreads();
    for (int off = 1; off < 1024; off <<= 1) {
        int v = (t >= off) ? psum[t - off] : 0;
        __syncthreads();
        psum[t] += v;
        __syncthreads();
    }
    int run = (t == 0) ? 0 : psum[t - 1];
    for (int i = 0; i < CH; ++i) {
        const int idx = base + i;
        if (idx < NNODES) {
            row_start[idx] = run;
            run += cnt[idx];
        }
    }
    if (t == 1023) row_start[NNODES] = psum[1023];
}

__global__ __launch_bounds__(256)
void scatter_edges(const int* __restrict__ src, const int* __restrict__ dst,
                   const int* __restrict__ et, int* __restrict__ cursor,
                   int* __restrict__ perm) {
    const int e = blockIdx.x * 256 + threadIdx.x;
    if (e >= NEDGES) return;
    const int d = dst[e];
    const int pos = atomicAdd(&cursor[d], 1);
    perm[pos] = src[e] | (et[e] << 16);
}

// ---------------------------------------------------------------------------
// a[v] = sum over incoming edges of Y[src, et*128..]  — one wave per node.
// ---------------------------------------------------------------------------
__global__ __launch_bounds__(256)
void edge_agg(const float* __restrict__ Y, const int* __restrict__ perm,
              const int* __restrict__ row_start, float* __restrict__ a) {
    const int node = blockIdx.x * 4 + (threadIdx.x >> 6);
    const int lane = threadIdx.x & 63;
    if (node >= NNODES) return;
    const int beg = row_start[node];
    const int end = row_start[node + 1];
    float2 acc = make_float2(0.f, 0.f);
    for (int i = beg; i < end; ++i) {
        const int p = perm[i];                    // wave-uniform
        const int s = p & 0xFFFF;
        const int t = p >> 16;
        const float2 v = *(const float2*)(Y + (size_t)s * 512 + t * DIM + lane * 2);
        acc.x += v.x;
        acc.y += v.y;
    }
    *(float2*)(a + (size_t)node * DIM + lane * 2) = acc;
}

// ---------------------------------------------------------------------------
// GRU gates
// ---------------------------------------------------------------------------
__device__ __forceinline__ float sigf(float x) { return 1.f / (1.f + expf(-x)); }

__global__ __launch_bounds__(256)
void gru_gate(const float* __restrict__ gi, const float* __restrict__ gh,
              const float* __restrict__ h_in, float* __restrict__ h_out) {
    const int idx = blockIdx.x * 256 + threadIdx.x;
    const int v = idx >> 5;
    const int q = (idx & 31) << 2;
    if (v >= NNODES) return;
    const size_t gbase = (size_t)v * 384 + q;
    const float4 ir = *(const float4*)(gi + gbase);
    const float4 iz = *(const float4*)(gi + gbase + 128);
    const float4 in4 = *(const float4*)(gi + gbase + 256);
    const float4 hr = *(const float4*)(gh + gbase);
    const float4 hz = *(const float4*)(gh + gbase + 128);
    const float4 hn = *(const float4*)(gh + gbase + 256);
    const float4 h4 = *(const float4*)(h_in + (size_t)v * DIM + q);
    float4 o;
    {
        const float r = sigf(ir.x + hr.x);
        const float z = sigf(iz.x + hz.x);
        const float n = tanhf(in4.x + r * hn.x);
        o.x = (1.f - z) * n + z * h4.x;
    }
    {
        const float r = sigf(ir.y + hr.y);
        const float z = sigf(iz.y + hz.y);
        const float n = tanhf(in4.y + r * hn.y);
        o.y = (1.f - z) * n + z * h4.y;
    }
    {
        const float r = sigf(ir.z + hr.z);
        const float z = sigf(iz.z + hz.z);
        const float n = tanhf(in4.z + r * hn.z);
        o.z = (1.f - z) * n + z * h4.z;
    }
    {
        const float r = sigf(ir.w + hr.w);
        const float z = sigf(iz.w + hz.w);
        const float n = tanhf(in4.w + r * hn.w);
        o.w = (1.f - z) * n + z * h4.w;
    }
    *(float4*)(h_out + (size_t)v * DIM + q) = o;
}

// ---------------------------------------------------------------------------
extern "C" void kernel_launch(void* const* d_in, const int* in_sizes, int n_in,
                              void* d_out, int out_size, void* d_ws, size_t ws_size,
                              hipStream_t stream) {
    const float* feat  = (const float*)d_in[0];
    const float* W_lin = (const float*)d_in[1];   // [4,128,128] == [512,128]
    const float* b_lin = (const float*)d_in[2];   // [512]
    const float* w_ih  = (const float*)d_in[3];   // [384,128]
    const float* w_hh  = (const float*)d_in[4];   // [384,128]
    const float* b_ih  = (const float*)d_in[5];   // [384]
    const float* b_hh  = (const float*)d_in[6];   // [384]
    const int*   src   = (const int*)d_in[7];
    const int*   dst   = (const int*)d_in[8];
    const int*   et    = (const int*)d_in[9];
    float* out = (float*)d_out;

    // ws layout (floats):
    //   h  : [0, 6.4M)
    //   Y  : [6.4M, 32M)          (50000*512)
    //   a  : [32M, 38.4M)
    //   gi : = Y base  [6.4M, 25.6M)   (Y dead after edge_agg)
    //   gh : [25.6M, 44.8M)            (overlaps Y-tail + a; both dead by then)
    //   ints after 44.8M floats: row_start[50001], perm[800000]
    //   cursor/cnt overlap `a` region (dead during CSR build at call start)
    float* h  = (float*)d_ws;
    float* Y  = h + (size_t)NNODES * DIM;
    float* a  = Y + (size_t)NNODES * 512;
    float* gi = Y;
    float* gh = gi + (size_t)NNODES * 384;
    int* row_start = (int*)(gh + (size_t)NNODES * 384);
    int* perm      = row_start + (NNODES + 1);
    int* cnt       = (int*)a;
    int* cursor    = cnt + NNODES + 64;

    const dim3 blk(256);
    const int mblocks = (NNODES + 127) / 128;   // 391
    const int eblocks = (NEDGES + 255) / 256;   // 3125

    // ---- build dst-CSR once (topology constant across steps) ----
    hipMemsetAsync(cnt, 0, (size_t)NNODES * sizeof(int), stream);
    hist_dst<<<dim3(eblocks), blk, 0, stream>>>(dst, cnt);
    scan_counts<<<dim3(1), dim3(1024), 0, stream>>>(cnt, row_start);
    hipMemcpyAsync(cursor, row_start, (size_t)NNODES * sizeof(int),
                   hipMemcpyDeviceToDevice, stream);
    scatter_edges<<<dim3(eblocks), blk, 0, stream>>>(src, dst, et, cursor, perm);

    for (int s = 0; s < 3; ++s) {
        const float* h_in = (s == 0) ? feat : h;
        float* h_out = (s == 2) ? out : h;

        // Y = h_in @ W_lin^T + b_lin   [50000, 512]
        gemm_mfma_bias<<<dim3(mblocks, 4), blk, 0, stream>>>(h_in, W_lin, b_lin, Y, NNODES, 512);
        // a[v] = sum_{e: dst=v} Y[src_e, et_e*128..]
        edge_agg<<<dim3((NNODES + 3) / 4), blk, 0, stream>>>(Y, perm, row_start, a);
        // gi = a @ w_ih^T + b_ih   [50000, 384]
        gemm_mfma_bias<<<dim3(mblocks, 3), blk, 0, stream>>>(a, w_ih, b_ih, gi, NNODES, 384);
        // gh = h_in @ w_hh^T + b_hh [50000, 384]
        gemm_mfma_bias<<<dim3(mblocks, 3), blk, 0, stream>>>(h_in, w_hh, b_hh, gh, NNODES, 384);
        // gates
        gru_gate<<<dim3((NNODES * 32 + 255) / 256), blk, 0, stream>>>(gi, gh, h_in, h_out);
    }
}

// Round 9
// 867.525 us; speedup vs baseline: 3.3673x; 1.1157x over previous
//
#include <hip/hip_runtime.h>
#include <hip/hip_bf16.h>
#include <math.h>

#define NNODES 50000
#define NEDGES 800000
#define DIM 128
#define NB_SCAN 98   // ceil(50000/512)

typedef __attribute__((ext_vector_type(8))) short bf16x8;
typedef __attribute__((ext_vector_type(4))) float f32x4;

// fp32 -> bf16 round-to-nearest-even
__device__ __forceinline__ short f2bf(float f) {
    unsigned int u = __float_as_uint(f);
    u += 0x7FFFu + ((u >> 16) & 1u);
    return (short)(u >> 16);
}

// ---------------------------------------------------------------------------
// C[M,N] = A[M,128] @ B[N,128]^T + bias[N], bf16 MFMA, fp32 accum.
// BM=BN=128, K=128 staged whole. 4 waves (2x2), 64x64 per wave.
// Fragment-linear LDS: staging writes and fragment reads both linear ->
// bank-conflict-free by construction. OutT: float or ushort (bf16 store).
// ---------------------------------------------------------------------------
template<typename OutT>
__global__ __launch_bounds__(256, 2)
void gemm_mfma_bias(const float* __restrict__ A, const float* __restrict__ B,
                    const float* __restrict__ bias, OutT* __restrict__ C,
                    int M, int N) {
    __shared__ short lsA[128 * 128];   // 32 KB
    __shared__ short lsB[128 * 128];   // 32 KB
    const int t = threadIdx.x;
    const int bm = blockIdx.x * 128;
    const int bn = blockIdx.y * 128;

    #pragma unroll
    for (int i = 0; i < 8; ++i) {
        const int u = i * 256 + t;
        const int fi = u >> 8;
        const int ks = (u >> 6) & 3;
        const int ln = u & 63;
        const int r = ln & 15;
        const int gk = ks * 32 + (ln >> 4) * 8;

        const int grow = bm + fi * 16 + r;
        bf16x8 va = {0, 0, 0, 0, 0, 0, 0, 0};
        if (grow < M) {
            const float4 f0 = *(const float4*)(A + (size_t)grow * DIM + gk);
            const float4 f1 = *(const float4*)(A + (size_t)grow * DIM + gk + 4);
            va[0] = f2bf(f0.x); va[1] = f2bf(f0.y); va[2] = f2bf(f0.z); va[3] = f2bf(f0.w);
            va[4] = f2bf(f1.x); va[5] = f2bf(f1.y); va[6] = f2bf(f1.z); va[7] = f2bf(f1.w);
        }
        *(bf16x8*)(lsA + (size_t)u * 8) = va;

        const int gcol = bn + fi * 16 + r;   // N % 128 == 0, no guard
        const float4 g0 = *(const float4*)(B + (size_t)gcol * DIM + gk);
        const float4 g1 = *(const float4*)(B + (size_t)gcol * DIM + gk + 4);
        bf16x8 vb;
        vb[0] = f2bf(g0.x); vb[1] = f2bf(g0.y); vb[2] = f2bf(g0.z); vb[3] = f2bf(g0.w);
        vb[4] = f2bf(g1.x); vb[5] = f2bf(g1.y); vb[6] = f2bf(g1.z); vb[7] = f2bf(g1.w);
        *(bf16x8*)(lsB + (size_t)u * 8) = vb;
    }
    __syncthreads();

    const int lane = t & 63;
    const int wave = t >> 6;
    const int wm = wave >> 1;
    const int wn = wave & 1;

    f32x4 acc[4][4];
    #pragma unroll
    for (int mi = 0; mi < 4; ++mi)
        #pragma unroll
        for (int nj = 0; nj < 4; ++nj)
            acc[mi][nj] = (f32x4){0.f, 0.f, 0.f, 0.f};

    #pragma unroll
    for (int ks = 0; ks < 4; ++ks) {
        bf16x8 af[4], bfr[4];
        #pragma unroll
        for (int mi = 0; mi < 4; ++mi)
            af[mi] = *(const bf16x8*)(lsA + (size_t)((((wm * 4 + mi) * 4 + ks) * 64 + lane)) * 8);
        #pragma unroll
        for (int nj = 0; nj < 4; ++nj)
            bfr[nj] = *(const bf16x8*)(lsB + (size_t)((((wn * 4 + nj) * 4 + ks) * 64 + lane)) * 8);
        #pragma unroll
        for (int mi = 0; mi < 4; ++mi)
            #pragma unroll
            for (int nj = 0; nj < 4; ++nj)
                acc[mi][nj] = __builtin_amdgcn_mfma_f32_16x16x32_bf16(
                    af[mi], bfr[nj], acc[mi][nj], 0, 0, 0);
    }

    // epilogue: col=lane&15, row=(lane>>4)*4+reg
    const int cr = lane >> 4;
    const int cc = lane & 15;
    float bv[4];
    #pragma unroll
    for (int nj = 0; nj < 4; ++nj)
        bv[nj] = bias[bn + wn * 64 + nj * 16 + cc];

    #pragma unroll
    for (int mi = 0; mi < 4; ++mi) {
        const int row0 = bm + wm * 64 + mi * 16 + cr * 4;
        #pragma unroll
        for (int reg = 0; reg < 4; ++reg) {
            const int row = row0 + reg;
            if (row >= M) continue;
            #pragma unroll
            for (int nj = 0; nj < 4; ++nj) {
                const int col = bn + wn * 64 + nj * 16 + cc;
                const float v = acc[mi][nj][reg] + bv[nj];
                if constexpr (sizeof(OutT) == 2)
                    C[(size_t)row * N + col] = (OutT)f2bf(v);
                else
                    C[(size_t)row * N + col] = v;
            }
        }
    }
}

// ---------------------------------------------------------------------------
// CSR-by-dst build (once per call). Multi-block scan replaces the old
// single-block scan_counts (93us -> ~10us): reduce / scan-partials / final.
// ---------------------------------------------------------------------------
__global__ __launch_bounds__(256)
void hist_dst(const int* __restrict__ dst, int* __restrict__ cnt) {
    const int e = blockIdx.x * 256 + threadIdx.x;
    if (e < NEDGES) atomicAdd(&cnt[dst[e]], 1);
}

__global__ __launch_bounds__(256)
void scan_blksum(const int* __restrict__ cnt, int* __restrict__ partial) {
    __shared__ int red[256];
    const int b = blockIdx.x, t = threadIdx.x;
    const int i0 = b * 512 + t * 2;
    const int v0 = (i0 < NNODES) ? cnt[i0] : 0;
    const int v1 = (i0 + 1 < NNODES) ? cnt[i0 + 1] : 0;
    red[t] = v0 + v1;
    __syncthreads();
    for (int off = 128; off > 0; off >>= 1) {
        if (t < off) red[t] += red[t + off];
        __syncthreads();
    }
    if (t == 0) partial[b] = red[0];
}

__global__ __launch_bounds__(128)
void scan_partials(const int* __restrict__ partial, int* __restrict__ bloff) {
    __shared__ int s[128];
    const int t = threadIdx.x;
    s[t] = (t < NB_SCAN) ? partial[t] : 0;
    __syncthreads();
    for (int off = 1; off < 128; off <<= 1) {
        const int v = (t >= off) ? s[t - off] : 0;
        __syncthreads();
        s[t] += v;
        __syncthreads();
    }
    if (t < NB_SCAN) bloff[t] = (t == 0) ? 0 : s[t - 1];
}

__global__ __launch_bounds__(256)
void scan_final(const int* __restrict__ cnt, const int* __restrict__ bloff,
                int* __restrict__ row_start, int* __restrict__ cursor) {
    __shared__ int s[256];
    const int b = blockIdx.x, t = threadIdx.x;
    const int i0 = b * 512 + t * 2;
    const int v0 = (i0 < NNODES) ? cnt[i0] : 0;
    const int v1 = (i0 + 1 < NNODES) ? cnt[i0 + 1] : 0;
    s[t] = v0 + v1;
    __syncthreads();
    for (int off = 1; off < 256; off <<= 1) {
        const int v = (t >= off) ? s[t - off] : 0;
        __syncthreads();
        s[t] += v;
        __syncthreads();
    }
    const int excl = bloff[b] + ((t == 0) ? 0 : s[t - 1]);
    if (i0 < NNODES) { row_start[i0] = excl; cursor[i0] = excl; }
    if (i0 + 1 < NNODES) { row_start[i0 + 1] = excl + v0; cursor[i0 + 1] = excl + v0; }
    if (b == 0 && t == 0) row_start[NNODES] = NEDGES;
}

__global__ __launch_bounds__(256)
void scatter_edges(const int* __restrict__ src, const int* __restrict__ dst,
                   const int* __restrict__ et, int* __restrict__ cursor,
                   int* __restrict__ perm) {
    const int e = blockIdx.x * 256 + threadIdx.x;
    if (e >= NEDGES) return;
    const int d = dst[e];
    const int pos = atomicAdd(&cursor[d], 1);
    perm[pos] = src[e] | (et[e] << 16);
}

// ---------------------------------------------------------------------------
// a[v] = sum over incoming edges of Ybf[src, et*128..] (bf16 gather, fp32 acc)
// ---------------------------------------------------------------------------
__global__ __launch_bounds__(256)
void edge_agg(const unsigned short* __restrict__ Ybf, const int* __restrict__ perm,
              const int* __restrict__ row_start, float* __restrict__ a) {
    const int node = blockIdx.x * 4 + (threadIdx.x >> 6);
    const int lane = threadIdx.x & 63;
    if (node >= NNODES) return;
    const int beg = row_start[node];
    const int end = row_start[node + 1];
    float2 acc = make_float2(0.f, 0.f);
    for (int i = beg; i < end; ++i) {
        const int p = perm[i];                    // wave-uniform
        const int s = p & 0xFFFF;
        const int t = p >> 16;
        const unsigned int u = *(const unsigned int*)(Ybf + (size_t)s * 512 + t * DIM + lane * 2);
        acc.x += __uint_as_float(u << 16);          // element lane*2
        acc.y += __uint_as_float(u & 0xFFFF0000u);  // element lane*2+1
    }
    *(float2*)(a + (size_t)node * DIM + lane * 2) = acc;
}

// ---------------------------------------------------------------------------
// GRU gates
// ---------------------------------------------------------------------------
__device__ __forceinline__ float sigf(float x) { return 1.f / (1.f + expf(-x)); }

__global__ __launch_bounds__(256)
void gru_gate(const float* __restrict__ gi, const float* __restrict__ gh,
              const float* __restrict__ h_in, float* __restrict__ h_out) {
    const int idx = blockIdx.x * 256 + threadIdx.x;
    const int v = idx >> 5;
    const int q = (idx & 31) << 2;
    if (v >= NNODES) return;
    const size_t gbase = (size_t)v * 384 + q;
    const float4 ir = *(const float4*)(gi + gbase);
    const float4 iz = *(const float4*)(gi + gbase + 128);
    const float4 in4 = *(const float4*)(gi + gbase + 256);
    const float4 hr = *(const float4*)(gh + gbase);
    const float4 hz = *(const float4*)(gh + gbase + 128);
    const float4 hn = *(const float4*)(gh + gbase + 256);
    const float4 h4 = *(const float4*)(h_in + (size_t)v * DIM + q);
    float4 o;
    {
        const float r = sigf(ir.x + hr.x);
        const float z = sigf(iz.x + hz.x);
        const float n = tanhf(in4.x + r * hn.x);
        o.x = (1.f - z) * n + z * h4.x;
    }
    {
        const float r = sigf(ir.y + hr.y);
        const float z = sigf(iz.y + hz.y);
        const float n = tanhf(in4.y + r * hn.y);
        o.y = (1.f - z) * n + z * h4.y;
    }
    {
        const float r = sigf(ir.z + hr.z);
        const float z = sigf(iz.z + hz.z);
        const float n = tanhf(in4.z + r * hn.z);
        o.z = (1.f - z) * n + z * h4.z;
    }
    {
        const float r = sigf(ir.w + hr.w);
        const float z = sigf(iz.w + hz.w);
        const float n = tanhf(in4.w + r * hn.w);
        o.w = (1.f - z) * n + z * h4.w;
    }
    *(float4*)(h_out + (size_t)v * DIM + q) = o;
}

// ---------------------------------------------------------------------------
extern "C" void kernel_launch(void* const* d_in, const int* in_sizes, int n_in,
                              void* d_out, int out_size, void* d_ws, size_t ws_size,
                              hipStream_t stream) {
    const float* feat  = (const float*)d_in[0];
    const float* W_lin = (const float*)d_in[1];   // [512,128]
    const float* b_lin = (const float*)d_in[2];   // [512]
    const float* w_ih  = (const float*)d_in[3];   // [384,128]
    const float* w_hh  = (const float*)d_in[4];   // [384,128]
    const float* b_ih  = (const float*)d_in[5];   // [384]
    const float* b_hh  = (const float*)d_in[6];   // [384]
    const int*   src   = (const int*)d_in[7];
    const int*   dst   = (const int*)d_in[8];
    const int*   et    = (const int*)d_in[9];
    float* out = (float*)d_out;

    // ws layout (float units):
    //   h  : [0, 6.4M)
    //   Y  : bf16 at [6.4M, 19.2M)  (50000*512 ushort = 51.2 MB)
    //   a  : [32M, 38.4M)
    //   gi : = Y base [6.4M, 25.6M)   (Y dead after edge_agg)
    //   gh : [25.6M, 44.8M)
    //   ints at 44.8M: row_start[50001], perm[800000], partial[98], bloff[98]
    //   cnt/cursor overlap `a` (dead during CSR build)
    float* h  = (float*)d_ws;
    float* Yf = h + (size_t)NNODES * DIM;
    unsigned short* Y = (unsigned short*)Yf;
    float* a  = Yf + (size_t)NNODES * 512;
    float* gi = Yf;
    float* gh = gi + (size_t)NNODES * 384;
    int* row_start = (int*)(gh + (size_t)NNODES * 384);
    int* perm      = row_start + (NNODES + 1);
    int* partial   = perm + NEDGES;
    int* bloff     = partial + NB_SCAN;
    int* cnt       = (int*)a;
    int* cursor    = cnt + NNODES + 64;

    const dim3 blk(256);
    const int mblocks = (NNODES + 127) / 128;   // 391
    const int eblocks = (NEDGES + 255) / 256;   // 3125

    // ---- build dst-CSR once (topology constant across steps) ----
    hipMemsetAsync(cnt, 0, (size_t)NNODES * sizeof(int), stream);
    hist_dst<<<dim3(eblocks), blk, 0, stream>>>(dst, cnt);
    scan_blksum<<<dim3(NB_SCAN), blk, 0, stream>>>(cnt, partial);
    scan_partials<<<dim3(1), dim3(128), 0, stream>>>(partial, bloff);
    scan_final<<<dim3(NB_SCAN), blk, 0, stream>>>(cnt, bloff, row_start, cursor);
    scatter_edges<<<dim3(eblocks), blk, 0, stream>>>(src, dst, et, cursor, perm);

    for (int s = 0; s < 3; ++s) {
        const float* h_in = (s == 0) ? feat : h;
        float* h_out = (s == 2) ? out : h;

        // Y(bf16) = h_in @ W_lin^T + b_lin   [50000, 512]
        gemm_mfma_bias<unsigned short><<<dim3(mblocks, 4), blk, 0, stream>>>(
            h_in, W_lin, b_lin, Y, NNODES, 512);
        // a[v] = sum_{e: dst=v} Y[src_e, et_e*128..]
        edge_agg<<<dim3((NNODES + 3) / 4), blk, 0, stream>>>(Y, perm, row_start, a);
        // gi = a @ w_ih^T + b_ih   [50000, 384]
        gemm_mfma_bias<float><<<dim3(mblocks, 3), blk, 0, stream>>>(
            a, w_ih, b_ih, gi, NNODES, 384);
        // gh = h_in @ w_hh^T + b_hh [50000, 384]
        gemm_mfma_bias<float><<<dim3(mblocks, 3), blk, 0, stream>>>(
            h_in, w_hh, b_hh, gh, NNODES, 384);
        // gates
        gru_gate<<<dim3((NNODES * 32 + 255) / 256), blk, 0, stream>>>(gi, gh, h_in, h_out);
    }
}

// Round 12
// 673.256 us; speedup vs baseline: 4.3389x; 1.2886x over previous
//
#include <hip/hip_runtime.h>
#include <hip/hip_bf16.h>
#include <math.h>
#include <stdint.h>

#define NNODES 50000
#define NEDGES 800000
#define DIM 128
#define NB_SCAN 98   // ceil(50000/512)

typedef __attribute__((ext_vector_type(8))) short bf16x8;
typedef __attribute__((ext_vector_type(4))) float f32x4;

// fp32 -> bf16 round-to-nearest-even
__device__ __forceinline__ short f2bf(float f) {
    unsigned int u = __float_as_uint(f);
    u += 0x7FFFu + ((u >> 16) & 1u);
    return (short)(u >> 16);
}

// ---------------------------------------------------------------------------
// One-time weight convert + swizzle into fragment-linear bf16 order.
// For each 128-col block cb of W[N][128]: unit ul=(fi*4+ks)*64+ln holds
// W[cb*128+fi*16+(ln&15)][ks*32+(ln>>4)*8 .. +8) as 8 bf16.
// ---------------------------------------------------------------------------
__global__ __launch_bounds__(256)
void conv_swz_w(const float* __restrict__ W, unsigned short* __restrict__ out,
                int nunits) {
    const int u = blockIdx.x * 256 + threadIdx.x;
    if (u >= nunits) return;
    const int cb = u >> 11;
    const int ul = u & 2047;
    const int fi = ul >> 8;
    const int ks = (ul >> 6) & 3;
    const int ln = ul & 63;
    const int row = cb * 128 + fi * 16 + (ln & 15);
    const int col = ks * 32 + (ln >> 4) * 8;
    const float4 f0 = *(const float4*)(W + (size_t)row * DIM + col);
    const float4 f1 = *(const float4*)(W + (size_t)row * DIM + col + 4);
    bf16x8 v;
    v[0] = f2bf(f0.x); v[1] = f2bf(f0.y); v[2] = f2bf(f0.z); v[3] = f2bf(f0.w);
    v[4] = f2bf(f1.x); v[5] = f2bf(f1.y); v[6] = f2bf(f1.z); v[7] = f2bf(f1.w);
    *(bf16x8*)(out + (size_t)u * 8) = v;
}

// ---------------------------------------------------------------------------
// C[M,N] = A[M,128] @ B[N,128]^T + bias[N], bf16 MFMA, fp32 accum.
// BM=BN=128, K=128 staged whole. 4 waves (2x2), 64x64 per wave.
// B comes PRE-SWIZZLED bf16 (conv_swz_w) -> staging is a linear 16B copy.
// A: InT = float (convert) or ushort (bf16 passthrough).
// OutT: float or ushort (bf16 store). Fragment-linear LDS: conflict-free.
// ---------------------------------------------------------------------------
template<typename InT, typename OutT>
__global__ __launch_bounds__(256, 2)
void gemm_mfma_bias(const InT* __restrict__ A, const unsigned short* __restrict__ Bswz,
                    const float* __restrict__ bias, OutT* __restrict__ C,
                    int M, int N) {
    __shared__ short lsA[128 * 128];   // 32 KB
    __shared__ short lsB[128 * 128];   // 32 KB
    const int t = threadIdx.x;
    const int bm = blockIdx.x * 128;
    const int bn = blockIdx.y * 128;

    // ---- B: linear copy of pre-swizzled column block ----
    const unsigned short* Bblk = Bswz + (size_t)blockIdx.y * (2048 * 8);
    #pragma unroll
    for (int i = 0; i < 8; ++i) {
        const int u = i * 256 + t;
        *(bf16x8*)(lsB + (size_t)u * 8) = *(const bf16x8*)(Bblk + (size_t)u * 8);
    }
    // ---- A: stage (convert if fp32) ----
    #pragma unroll
    for (int i = 0; i < 8; ++i) {
        const int u = i * 256 + t;
        const int fi = u >> 8;
        const int ks = (u >> 6) & 3;
        const int ln = u & 63;
        const int r = ln & 15;
        const int gk = ks * 32 + (ln >> 4) * 8;
        const int grow = bm + fi * 16 + r;
        bf16x8 va = {0, 0, 0, 0, 0, 0, 0, 0};
        if (grow < M) {
            if constexpr (sizeof(InT) == 2) {
                va = *(const bf16x8*)(A + (size_t)grow * DIM + gk);
            } else {
                const float4 f0 = *(const float4*)(A + (size_t)grow * DIM + gk);
                const float4 f1 = *(const float4*)(A + (size_t)grow * DIM + gk + 4);
                va[0] = f2bf(f0.x); va[1] = f2bf(f0.y); va[2] = f2bf(f0.z); va[3] = f2bf(f0.w);
                va[4] = f2bf(f1.x); va[5] = f2bf(f1.y); va[6] = f2bf(f1.z); va[7] = f2bf(f1.w);
            }
        }
        *(bf16x8*)(lsA + (size_t)u * 8) = va;
    }
    __syncthreads();

    const int lane = t & 63;
    const int wave = t >> 6;
    const int wm = wave >> 1;
    const int wn = wave & 1;

    f32x4 acc[4][4];
    #pragma unroll
    for (int mi = 0; mi < 4; ++mi)
        #pragma unroll
        for (int nj = 0; nj < 4; ++nj)
            acc[mi][nj] = (f32x4){0.f, 0.f, 0.f, 0.f};

    #pragma unroll
    for (int ks = 0; ks < 4; ++ks) {
        bf16x8 af[4], bfr[4];
        #pragma unroll
        for (int mi = 0; mi < 4; ++mi)
            af[mi] = *(const bf16x8*)(lsA + (size_t)((((wm * 4 + mi) * 4 + ks) * 64 + lane)) * 8);
        #pragma unroll
        for (int nj = 0; nj < 4; ++nj)
            bfr[nj] = *(const bf16x8*)(lsB + (size_t)((((wn * 4 + nj) * 4 + ks) * 64 + lane)) * 8);
        #pragma unroll
        for (int mi = 0; mi < 4; ++mi)
            #pragma unroll
            for (int nj = 0; nj < 4; ++nj)
                acc[mi][nj] = __builtin_amdgcn_mfma_f32_16x16x32_bf16(
                    af[mi], bfr[nj], acc[mi][nj], 0, 0, 0);
    }

    // epilogue: col=lane&15, row=(lane>>4)*4+reg
    const int cr = lane >> 4;
    const int cc = lane & 15;
    float bv[4];
    #pragma unroll
    for (int nj = 0; nj < 4; ++nj)
        bv[nj] = bias[bn + wn * 64 + nj * 16 + cc];

    #pragma unroll
    for (int mi = 0; mi < 4; ++mi) {
        const int row0 = bm + wm * 64 + mi * 16 + cr * 4;
        #pragma unroll
        for (int reg = 0; reg < 4; ++reg) {
            const int row = row0 + reg;
            if (row >= M) continue;
            #pragma unroll
            for (int nj = 0; nj < 4; ++nj) {
                const int col = bn + wn * 64 + nj * 16 + cc;
                const float v = acc[mi][nj][reg] + bv[nj];
                if constexpr (sizeof(OutT) == 2)
                    C[(size_t)row * N + col] = (OutT)f2bf(v);
                else
                    C[(size_t)row * N + col] = v;
            }
        }
    }
}

// ---------------------------------------------------------------------------
// CSR-by-dst build (once per call), multi-block scan.
// ---------------------------------------------------------------------------
__global__ __launch_bounds__(256)
void hist_dst(const int* __restrict__ dst, int* __restrict__ cnt) {
    const int e = blockIdx.x * 256 + threadIdx.x;
    if (e < NEDGES) atomicAdd(&cnt[dst[e]], 1);
}

__global__ __launch_bounds__(256)
void scan_blksum(const int* __restrict__ cnt, int* __restrict__ partial) {
    __shared__ int red[256];
    const int b = blockIdx.x, t = threadIdx.x;
    const int i0 = b * 512 + t * 2;
    const int v0 = (i0 < NNODES) ? cnt[i0] : 0;
    const int v1 = (i0 + 1 < NNODES) ? cnt[i0 + 1] : 0;
    red[t] = v0 + v1;
    __syncthreads();
    for (int off = 128; off > 0; off >>= 1) {
        if (t < off) red[t] += red[t + off];
        __syncthreads();
    }
    if (t == 0) partial[b] = red[0];
}

__global__ __launch_bounds__(128)
void scan_partials(const int* __restrict__ partial, int* __restrict__ bloff) {
    __shared__ int s[128];
    const int t = threadIdx.x;
    s[t] = (t < NB_SCAN) ? partial[t] : 0;
    __syncthreads();
    for (int off = 1; off < 128; off <<= 1) {
        const int v = (t >= off) ? s[t - off] : 0;
        __syncthreads();
        s[t] += v;
        __syncthreads();
    }
    if (t < NB_SCAN) bloff[t] = (t == 0) ? 0 : s[t - 1];
}

__global__ __launch_bounds__(256)
void scan_final(const int* __restrict__ cnt, const int* __restrict__ bloff,
                int* __restrict__ row_start, int* __restrict__ cursor) {
    __shared__ int s[256];
    const int b = blockIdx.x, t = threadIdx.x;
    const int i0 = b * 512 + t * 2;
    const int v0 = (i0 < NNODES) ? cnt[i0] : 0;
    const int v1 = (i0 + 1 < NNODES) ? cnt[i0 + 1] : 0;
    s[t] = v0 + v1;
    __syncthreads();
    for (int off = 1; off < 256; off <<= 1) {
        const int v = (t >= off) ? s[t - off] : 0;
        __syncthreads();
        s[t] += v;
        __syncthreads();
    }
    const int excl = bloff[b] + ((t == 0) ? 0 : s[t - 1]);
    if (i0 < NNODES) { row_start[i0] = excl; cursor[i0] = excl; }
    if (i0 + 1 < NNODES) { row_start[i0 + 1] = excl + v0; cursor[i0 + 1] = excl + v0; }
    if (b == 0 && t == 0) row_start[NNODES] = NEDGES;
}

__global__ __launch_bounds__(256)
void scatter_edges(const int* __restrict__ src, const int* __restrict__ dst,
                   const int* __restrict__ et, int* __restrict__ cursor,
                   int* __restrict__ perm) {
    const int e = blockIdx.x * 256 + threadIdx.x;
    if (e >= NEDGES) return;
    const int d = dst[e];
    const int pos = atomicAdd(&cursor[d], 1);
    perm[pos] = src[e] | (et[e] << 16);
}

// ---------------------------------------------------------------------------
// a[v] = sum over incoming edges of Ybf[src, et*128..], 8-wide pipelined
// gathers (8 independent loads in flight per wave). Output bf16 (identical
// rounding to what the consumer GEMM would apply).
// ---------------------------------------------------------------------------
__global__ __launch_bounds__(256)
void edge_agg(const unsigned short* __restrict__ Ybf, const int* __restrict__ perm,
              const int* __restrict__ row_start, unsigned short* __restrict__ abf) {
    const int node = blockIdx.x * 4 + (threadIdx.x >> 6);
    const int lane = threadIdx.x & 63;
    if (node >= NNODES) return;
    const int beg = row_start[node];
    const int end = row_start[node + 1];
    float ax = 0.f, ay = 0.f;
    const int l2 = lane * 2;
    int i = beg;
    for (; i + 8 <= end; i += 8) {
        const int p0 = perm[i + 0], p1 = perm[i + 1], p2 = perm[i + 2], p3 = perm[i + 3];
        const int p4 = perm[i + 4], p5 = perm[i + 5], p6 = perm[i + 6], p7 = perm[i + 7];
        const unsigned int u0 = *(const unsigned int*)(Ybf + (size_t)(p0 & 0xFFFF) * 512 + (p0 >> 16) * DIM + l2);
        const unsigned int u1 = *(const unsigned int*)(Ybf + (size_t)(p1 & 0xFFFF) * 512 + (p1 >> 16) * DIM + l2);
        const unsigned int u2 = *(const unsigned int*)(Ybf + (size_t)(p2 & 0xFFFF) * 512 + (p2 >> 16) * DIM + l2);
        const unsigned int u3 = *(const unsigned int*)(Ybf + (size_t)(p3 & 0xFFFF) * 512 + (p3 >> 16) * DIM + l2);
        const unsigned int u4 = *(const unsigned int*)(Ybf + (size_t)(p4 & 0xFFFF) * 512 + (p4 >> 16) * DIM + l2);
        const unsigned int u5 = *(const unsigned int*)(Ybf + (size_t)(p5 & 0xFFFF) * 512 + (p5 >> 16) * DIM + l2);
        const unsigned int u6 = *(const unsigned int*)(Ybf + (size_t)(p6 & 0xFFFF) * 512 + (p6 >> 16) * DIM + l2);
        const unsigned int u7 = *(const unsigned int*)(Ybf + (size_t)(p7 & 0xFFFF) * 512 + (p7 >> 16) * DIM + l2);
        ax += __uint_as_float(u0 << 16); ay += __uint_as_float(u0 & 0xFFFF0000u);
        ax += __uint_as_float(u1 << 16); ay += __uint_as_float(u1 & 0xFFFF0000u);
        ax += __uint_as_float(u2 << 16); ay += __uint_as_float(u2 & 0xFFFF0000u);
        ax += __uint_as_float(u3 << 16); ay += __uint_as_float(u3 & 0xFFFF0000u);
        ax += __uint_as_float(u4 << 16); ay += __uint_as_float(u4 & 0xFFFF0000u);
        ax += __uint_as_float(u5 << 16); ay += __uint_as_float(u5 & 0xFFFF0000u);
        ax += __uint_as_float(u6 << 16); ay += __uint_as_float(u6 & 0xFFFF0000u);
        ax += __uint_as_float(u7 << 16); ay += __uint_as_float(u7 & 0xFFFF0000u);
    }
    for (; i < end; ++i) {
        const int p = perm[i];
        const unsigned int u = *(const unsigned int*)(Ybf + (size_t)(p & 0xFFFF) * 512 + (p >> 16) * DIM + l2);
        ax += __uint_as_float(u << 16);
        ay += __uint_as_float(u & 0xFFFF0000u);
    }
    const unsigned int bx = (unsigned short)f2bf(ax);
    const unsigned int by = (unsigned short)f2bf(ay);
    *(unsigned int*)(abf + (size_t)node * DIM + l2) = (by << 16) | bx;
}

// ---------------------------------------------------------------------------
// GRU gates
// ---------------------------------------------------------------------------
__device__ __forceinline__ float sigf(float x) { return 1.f / (1.f + expf(-x)); }

__global__ __launch_bounds__(256)
void gru_gate(const float* __restrict__ gi, const float* __restrict__ gh,
              const float* __restrict__ h_in, float* __restrict__ h_out) {
    const int idx = blockIdx.x * 256 + threadIdx.x;
    const int v = idx >> 5;
    const int q = (idx & 31) << 2;
    if (v >= NNODES) return;
    const size_t gbase = (size_t)v * 384 + q;
    const float4 ir = *(const float4*)(gi + gbase);
    const float4 iz = *(const float4*)(gi + gbase + 128);
    const float4 in4 = *(const float4*)(gi + gbase + 256);
    const float4 hr = *(const float4*)(gh + gbase);
    const float4 hz = *(const float4*)(gh + gbase + 128);
    const float4 hn = *(const float4*)(gh + gbase + 256);
    const float4 h4 = *(const float4*)(h_in + (size_t)v * DIM + q);
    float4 o;
    {
        const float r = sigf(ir.x + hr.x);
        const float z = sigf(iz.x + hz.x);
        const float n = tanhf(in4.x + r * hn.x);
        o.x = (1.f - z) * n + z * h4.x;
    }
    {
        const float r = sigf(ir.y + hr.y);
        const float z = sigf(iz.y + hz.y);
        const float n = tanhf(in4.y + r * hn.y);
        o.y = (1.f - z) * n + z * h4.y;
    }
    {
        const float r = sigf(ir.z + hr.z);
        const float z = sigf(iz.z + hz.z);
        const float n = tanhf(in4.z + r * hn.z);
        o.z = (1.f - z) * n + z * h4.z;
    }
    {
        const float r = sigf(ir.w + hr.w);
        const float z = sigf(iz.w + hz.w);
        const float n = tanhf(in4.w + r * hn.w);
        o.w = (1.f - z) * n + z * h4.w;
    }
    *(float4*)(h_out + (size_t)v * DIM + q) = o;
}

// ---------------------------------------------------------------------------
extern "C" void kernel_launch(void* const* d_in, const int* in_sizes, int n_in,
                              void* d_out, int out_size, void* d_ws, size_t ws_size,
                              hipStream_t stream) {
    const float* feat  = (const float*)d_in[0];
    const float* W_lin = (const float*)d_in[1];   // [512,128]
    const float* b_lin = (const float*)d_in[2];   // [512]
    const float* w_ih  = (const float*)d_in[3];   // [384,128]
    const float* w_hh  = (const float*)d_in[4];   // [384,128]
    const float* b_ih  = (const float*)d_in[5];   // [384]
    const float* b_hh  = (const float*)d_in[6];   // [384]
    const int*   src   = (const int*)d_in[7];
    const int*   dst   = (const int*)d_in[8];
    const int*   et    = (const int*)d_in[9];
    float* out = (float*)d_out;

    // ws layout (float units):
    //   h   : [0, 6.4M)
    //   Y   : bf16 at [6.4M, 19.2M)
    //   gi  : [6.4M, 25.6M)            (over Y; Y dead after edge_agg)
    //   gh  : [25.6M, 44.8M)
    //   abf : bf16 at [32M, 35.2M)     (over gh-tail; liveness disjoint by order)
    //   ints at 44.8M: row_start[50001], perm[800000], partial[98], bloff[98]
    //   wswz: bf16 weights after ints (persistent, ~0.33 MB)
    //   cnt/cursor at abf base region (dead during CSR build only)
    float* h  = (float*)d_ws;
    float* Yf = h + (size_t)NNODES * DIM;
    unsigned short* Y = (unsigned short*)Yf;
    float* abase = Yf + (size_t)NNODES * 512;            // 32M
    unsigned short* abf = (unsigned short*)abase;
    float* gi = Yf;
    float* gh = gi + (size_t)NNODES * 384;
    int* row_start = (int*)(gh + (size_t)NNODES * 384);  // 44.8M
    int* perm      = row_start + (NNODES + 1);
    int* partial   = perm + NEDGES;
    int* bloff     = partial + NB_SCAN;
    unsigned short* wswz = (unsigned short*)(((uintptr_t)(bloff + NB_SCAN) + 15) & ~(uintptr_t)15);
    unsigned short* wlin_swz = wswz;                  // 512*128 = 65536
    unsigned short* wih_swz  = wswz + 65536;          // 384*128 = 49152
    unsigned short* whh_swz  = wih_swz + 49152;       // 49152
    int* cnt    = (int*)abase;
    int* cursor = cnt + NNODES + 64;

    const dim3 blk(256);
    const int mblocks = (NNODES + 127) / 128;   // 391
    const int eblocks = (NEDGES + 255) / 256;   // 3125

    // ---- one-time: weight convert+swizzle, dst-CSR build ----
    conv_swz_w<<<dim3(32), blk, 0, stream>>>(W_lin, wlin_swz, 8192);
    conv_swz_w<<<dim3(24), blk, 0, stream>>>(w_ih, wih_swz, 6144);
    conv_swz_w<<<dim3(24), blk, 0, stream>>>(w_hh, whh_swz, 6144);
    hipMemsetAsync(cnt, 0, (size_t)NNODES * sizeof(int), stream);
    hist_dst<<<dim3(eblocks), blk, 0, stream>>>(dst, cnt);
    scan_blksum<<<dim3(NB_SCAN), blk, 0, stream>>>(cnt, partial);
    scan_partials<<<dim3(1), dim3(128), 0, stream>>>(partial, bloff);
    scan_final<<<dim3(NB_SCAN), blk, 0, stream>>>(cnt, bloff, row_start, cursor);
    scatter_edges<<<dim3(eblocks), blk, 0, stream>>>(src, dst, et, cursor, perm);

    for (int s = 0; s < 3; ++s) {
        const float* h_in = (s == 0) ? feat : h;
        float* h_out = (s == 2) ? out : h;

        // Y(bf16) = h_in @ W_lin^T + b_lin   [50000, 512]
        gemm_mfma_bias<float, unsigned short><<<dim3(mblocks, 4), blk, 0, stream>>>(
            h_in, wlin_swz, b_lin, Y, NNODES, 512);
        // abf[v] = sum_{e: dst=v} Y[src_e, et_e*128..]   (bf16 out)
        edge_agg<<<dim3((NNODES + 3) / 4), blk, 0, stream>>>(Y, perm, row_start, abf);
        // gi = abf @ w_ih^T + b_ih   [50000, 384]
        gemm_mfma_bias<unsigned short, float><<<dim3(mblocks, 3), blk, 0, stream>>>(
            abf, wih_swz, b_ih, gi, NNODES, 384);
        // gh = h_in @ w_hh^T + b_hh  [50000, 384]
        gemm_mfma_bias<float, float><<<dim3(mblocks, 3), blk, 0, stream>>>(
            h_in, whh_swz, b_hh, gh, NNODES, 384);
        // gates
        gru_gate<<<dim3((NNODES * 32 + 255) / 256), blk, 0, stream>>>(gi, gh, h_in, h_out);
    }
}

// Round 14
// 621.244 us; speedup vs baseline: 4.7022x; 1.0837x over previous
//
#include <hip/hip_runtime.h>
#include <hip/hip_bf16.h>
#include <math.h>
#include <stdint.h>

#define NNODES 50000
#define NEDGES 800000
#define DIM 128
#define NB_SCAN 98   // ceil(50000/512)

typedef __attribute__((ext_vector_type(8))) short bf16x8;
typedef __attribute__((ext_vector_type(4))) float f32x4;

// fp32 -> bf16 round-to-nearest-even
__device__ __forceinline__ short f2bf(float f) {
    unsigned int u = __float_as_uint(f);
    u += 0x7FFFu + ((u >> 16) & 1u);
    return (short)(u >> 16);
}

// ---------------------------------------------------------------------------
// One-time weight convert + swizzle into fragment-linear bf16 order (K=128).
// For each 128-col block cb of W[N][128]: unit ul=(fi*4+ks)*64+ln holds
// W[cb*128+fi*16+(ln&15)][ks*32+(ln>>4)*8 .. +8) as 8 bf16.
// ---------------------------------------------------------------------------
__global__ __launch_bounds__(256)
void conv_swz_w(const float* __restrict__ W, unsigned short* __restrict__ out,
                int nunits) {
    const int u = blockIdx.x * 256 + threadIdx.x;
    if (u >= nunits) return;
    const int cb = u >> 11;
    const int ul = u & 2047;
    const int fi = ul >> 8;
    const int ks = (ul >> 6) & 3;
    const int ln = ul & 63;
    const int row = cb * 128 + fi * 16 + (ln & 15);
    const int col = ks * 32 + (ln >> 4) * 8;
    const float4 f0 = *(const float4*)(W + (size_t)row * DIM + col);
    const float4 f1 = *(const float4*)(W + (size_t)row * DIM + col + 4);
    bf16x8 v;
    v[0] = f2bf(f0.x); v[1] = f2bf(f0.y); v[2] = f2bf(f0.z); v[3] = f2bf(f0.w);
    v[4] = f2bf(f1.x); v[5] = f2bf(f1.y); v[6] = f2bf(f1.z); v[7] = f2bf(f1.w);
    *(bf16x8*)(out + (size_t)u * 8) = v;
}

// ---------------------------------------------------------------------------
// Build swizzled W_big[512][256] for the fused GRU GEMM.
// Output cols n (= W_big row): 0-255 r/z concat [w_ih|w_hh]; 256-383 [wih_n|0];
// 384-511 [0|whh_n]. K layout: kb in {0,1} chunks of 128.
// unit u: nb=u>>12, kb=(u>>11)&1, ul=u&2047 (fi,ks,ln as usual).
// ---------------------------------------------------------------------------
__global__ __launch_bounds__(256)
void conv_swz_wbig(const float* __restrict__ w_ih, const float* __restrict__ w_hh,
                   unsigned short* __restrict__ out) {
    const int u = blockIdx.x * 256 + threadIdx.x;
    if (u >= 16384) return;
    const int nb = u >> 12;
    const int kb = (u >> 11) & 1;
    const int ul = u & 2047;
    const int fi = ul >> 8;
    const int ks = (ul >> 6) & 3;
    const int ln = ul & 63;
    const int nrow = nb * 128 + fi * 16 + (ln & 15);   // 0..511
    const int kc0 = ks * 32 + (ln >> 4) * 8;           // 0..120 within chunk
    bf16x8 v;
    #pragma unroll
    for (int j = 0; j < 8; ++j) {
        const int kc = kb * 128 + kc0 + j;             // 0..255
        float f = 0.f;
        if (nrow < 256) {
            f = (kc < 128) ? w_ih[(size_t)nrow * DIM + kc]
                           : w_hh[(size_t)nrow * DIM + (kc - 128)];
        } else if (nrow < 384) {
            if (kc < 128) f = w_ih[(size_t)nrow * DIM + kc];           // n-gate i rows
        } else {
            if (kc >= 128) f = w_hh[(size_t)(nrow - 128) * DIM + (kc - 128)];
        }
        v[j] = f2bf(f);
    }
    *(bf16x8*)(out + (size_t)u * 8) = v;
}

__global__ __launch_bounds__(256)
void build_bias_big(const float* __restrict__ b_ih, const float* __restrict__ b_hh,
                    float* __restrict__ bias_big) {
    const int n = blockIdx.x * 256 + threadIdx.x;
    if (n >= 512) return;
    float b;
    if (n < 256)      b = b_ih[n] + b_hh[n];
    else if (n < 384) b = b_ih[n];
    else              b = b_hh[n - 128];
    bias_big[n] = b;
}

// feat -> bf16 into ah[:,128:256]
__global__ __launch_bounds__(256)
void feat2bf(const float* __restrict__ feat, unsigned short* __restrict__ ah) {
    const int idx = blockIdx.x * 256 + threadIdx.x;
    const int v = idx >> 5;
    const int q = (idx & 31) << 2;
    if (v >= NNODES) return;
    const float4 f = *(const float4*)(feat + (size_t)v * DIM + q);
    ushort4 o;
    o.x = (unsigned short)f2bf(f.x); o.y = (unsigned short)f2bf(f.y);
    o.z = (unsigned short)f2bf(f.z); o.w = (unsigned short)f2bf(f.w);
    *(ushort4*)(ah + (size_t)v * 256 + 128 + q) = o;
}

// ---------------------------------------------------------------------------
// C[M,N] = A[M,K] @ B[N,K]^T + bias[N]; K = KB*128. bf16 MFMA, fp32 accum.
// A bf16 with row stride lda. B pre-swizzled per (nb,kb). BM=BN=128.
// OutT: float or ushort (bf16 store).
// ---------------------------------------------------------------------------
template<int KB, typename OutT>
__global__ __launch_bounds__(256, 2)
void gemm_mfma_bias(const unsigned short* __restrict__ A, int lda,
                    const unsigned short* __restrict__ Bswz,
                    const float* __restrict__ bias, OutT* __restrict__ C,
                    int M, int N) {
    __shared__ short lsA[128 * 128];   // 32 KB (one K-chunk)
    __shared__ short lsB[128 * 128];   // 32 KB
    const int t = threadIdx.x;
    const int bm = blockIdx.x * 128;
    const int lane = t & 63;
    const int wave = t >> 6;
    const int wm = wave >> 1;
    const int wn = wave & 1;

    f32x4 acc[4][4];
    #pragma unroll
    for (int mi = 0; mi < 4; ++mi)
        #pragma unroll
        for (int nj = 0; nj < 4; ++nj)
            acc[mi][nj] = (f32x4){0.f, 0.f, 0.f, 0.f};

    for (int kb = 0; kb < KB; ++kb) {
        if (kb) __syncthreads();   // protect LDS reuse across chunks
        // B: linear copy of pre-swizzled (nb,kb) block
        const unsigned short* Bblk = Bswz + ((size_t)blockIdx.y * KB + kb) * (2048 * 8);
        #pragma unroll
        for (int i = 0; i < 8; ++i) {
            const int u = i * 256 + t;
            *(bf16x8*)(lsB + (size_t)u * 8) = *(const bf16x8*)(Bblk + (size_t)u * 8);
        }
        // A: bf16 passthrough staging of chunk kb
        #pragma unroll
        for (int i = 0; i < 8; ++i) {
            const int u = i * 256 + t;
            const int fi = u >> 8;
            const int ks = (u >> 6) & 3;
            const int ln = u & 63;
            const int r = ln & 15;
            const int gk = kb * 128 + ks * 32 + (ln >> 4) * 8;
            const int grow = bm + fi * 16 + r;
            bf16x8 va = {0, 0, 0, 0, 0, 0, 0, 0};
            if (grow < M) va = *(const bf16x8*)(A + (size_t)grow * lda + gk);
            *(bf16x8*)(lsA + (size_t)u * 8) = va;
        }
        __syncthreads();

        #pragma unroll
        for (int ks = 0; ks < 4; ++ks) {
            bf16x8 af[4], bfr[4];
            #pragma unroll
            for (int mi = 0; mi < 4; ++mi)
                af[mi] = *(const bf16x8*)(lsA + (size_t)((((wm * 4 + mi) * 4 + ks) * 64 + lane)) * 8);
            #pragma unroll
            for (int nj = 0; nj < 4; ++nj)
                bfr[nj] = *(const bf16x8*)(lsB + (size_t)((((wn * 4 + nj) * 4 + ks) * 64 + lane)) * 8);
            #pragma unroll
            for (int mi = 0; mi < 4; ++mi)
                #pragma unroll
                for (int nj = 0; nj < 4; ++nj)
                    acc[mi][nj] = __builtin_amdgcn_mfma_f32_16x16x32_bf16(
                        af[mi], bfr[nj], acc[mi][nj], 0, 0, 0);
        }
    }

    // epilogue: col=lane&15, row=(lane>>4)*4+reg
    const int bn = blockIdx.y * 128;
    const int cr = lane >> 4;
    const int cc = lane & 15;
    float bv[4];
    #pragma unroll
    for (int nj = 0; nj < 4; ++nj)
        bv[nj] = bias[bn + wn * 64 + nj * 16 + cc];

    #pragma unroll
    for (int mi = 0; mi < 4; ++mi) {
        const int row0 = bm + wm * 64 + mi * 16 + cr * 4;
        #pragma unroll
        for (int reg = 0; reg < 4; ++reg) {
            const int row = row0 + reg;
            if (row >= M) continue;
            #pragma unroll
            for (int nj = 0; nj < 4; ++nj) {
                const int col = bn + wn * 64 + nj * 16 + cc;
                const float v = acc[mi][nj][reg] + bv[nj];
                if constexpr (sizeof(OutT) == 2)
                    C[(size_t)row * N + col] = (OutT)f2bf(v);
                else
                    C[(size_t)row * N + col] = v;
            }
        }
    }
}

// ---------------------------------------------------------------------------
// CSR-by-dst build (once per call), multi-block scan.
// ---------------------------------------------------------------------------
__global__ __launch_bounds__(256)
void hist_dst(const int* __restrict__ dst, int* __restrict__ cnt) {
    const int e = blockIdx.x * 256 + threadIdx.x;
    if (e < NEDGES) atomicAdd(&cnt[dst[e]], 1);
}

__global__ __launch_bounds__(256)
void scan_blksum(const int* __restrict__ cnt, int* __restrict__ partial) {
    __shared__ int red[256];
    const int b = blockIdx.x, t = threadIdx.x;
    const int i0 = b * 512 + t * 2;
    const int v0 = (i0 < NNODES) ? cnt[i0] : 0;
    const int v1 = (i0 + 1 < NNODES) ? cnt[i0 + 1] : 0;
    red[t] = v0 + v1;
    __syncthreads();
    for (int off = 128; off > 0; off >>= 1) {
        if (t < off) red[t] += red[t + off];
        __syncthreads();
    }
    if (t == 0) partial[b] = red[0];
}

__global__ __launch_bounds__(128)
void scan_partials(const int* __restrict__ partial, int* __restrict__ bloff) {
    __shared__ int s[128];
    const int t = threadIdx.x;
    s[t] = (t < NB_SCAN) ? partial[t] : 0;
    __syncthreads();
    for (int off = 1; off < 128; off <<= 1) {
        const int v = (t >= off) ? s[t - off] : 0;
        __syncthreads();
        s[t] += v;
        __syncthreads();
    }
    if (t < NB_SCAN) bloff[t] = (t == 0) ? 0 : s[t - 1];
}

__global__ __launch_bounds__(256)
void scan_final(const int* __restrict__ cnt, const int* __restrict__ bloff,
                int* __restrict__ row_start, int* __restrict__ cursor) {
    __shared__ int s[256];
    const int b = blockIdx.x, t = threadIdx.x;
    const int i0 = b * 512 + t * 2;
    const int v0 = (i0 < NNODES) ? cnt[i0] : 0;
    const int v1 = (i0 + 1 < NNODES) ? cnt[i0 + 1] : 0;
    s[t] = v0 + v1;
    __syncthreads();
    for (int off = 1; off < 256; off <<= 1) {
        const int v = (t >= off) ? s[t - off] : 0;
        __syncthreads();
        s[t] += v;
        __syncthreads();
    }
    const int excl = bloff[b] + ((t == 0) ? 0 : s[t - 1]);
    if (i0 < NNODES) { row_start[i0] = excl; cursor[i0] = excl; }
    if (i0 + 1 < NNODES) { row_start[i0 + 1] = excl + v0; cursor[i0 + 1] = excl + v0; }
    if (b == 0 && t == 0) row_start[NNODES] = NEDGES;
}

__global__ __launch_bounds__(256)
void scatter_edges(const int* __restrict__ src, const int* __restrict__ dst,
                   const int* __restrict__ et, int* __restrict__ cursor,
                   int* __restrict__ perm) {
    const int e = blockIdx.x * 256 + threadIdx.x;
    if (e >= NEDGES) return;
    const int d = dst[e];
    const int pos = atomicAdd(&cursor[d], 1);
    perm[pos] = src[e] | (et[e] << 16);
}

// ---------------------------------------------------------------------------
// ah[v][0:128] = sum over incoming edges of Ybf[src, et*128..]; 8-wide
// pipelined gathers, fp32 accum, bf16 out (row stride 256).
// ---------------------------------------------------------------------------
__global__ __launch_bounds__(256)
void edge_agg(const unsigned short* __restrict__ Ybf, const int* __restrict__ perm,
              const int* __restrict__ row_start, unsigned short* __restrict__ ah) {
    const int node = blockIdx.x * 4 + (threadIdx.x >> 6);
    const int lane = threadIdx.x & 63;
    if (node >= NNODES) return;
    const int beg = row_start[node];
    const int end = row_start[node + 1];
    float ax = 0.f, ay = 0.f;
    const int l2 = lane * 2;
    int i = beg;
    for (; i + 8 <= end; i += 8) {
        const int p0 = perm[i + 0], p1 = perm[i + 1], p2 = perm[i + 2], p3 = perm[i + 3];
        const int p4 = perm[i + 4], p5 = perm[i + 5], p6 = perm[i + 6], p7 = perm[i + 7];
        const unsigned int u0 = *(const unsigned int*)(Ybf + (size_t)(p0 & 0xFFFF) * 512 + (p0 >> 16) * DIM + l2);
        const unsigned int u1 = *(const unsigned int*)(Ybf + (size_t)(p1 & 0xFFFF) * 512 + (p1 >> 16) * DIM + l2);
        const unsigned int u2 = *(const unsigned int*)(Ybf + (size_t)(p2 & 0xFFFF) * 512 + (p2 >> 16) * DIM + l2);
        const unsigned int u3 = *(const unsigned int*)(Ybf + (size_t)(p3 & 0xFFFF) * 512 + (p3 >> 16) * DIM + l2);
        const unsigned int u4 = *(const unsigned int*)(Ybf + (size_t)(p4 & 0xFFFF) * 512 + (p4 >> 16) * DIM + l2);
        const unsigned int u5 = *(const unsigned int*)(Ybf + (size_t)(p5 & 0xFFFF) * 512 + (p5 >> 16) * DIM + l2);
        const unsigned int u6 = *(const unsigned int*)(Ybf + (size_t)(p6 & 0xFFFF) * 512 + (p6 >> 16) * DIM + l2);
        const unsigned int u7 = *(const unsigned int*)(Ybf + (size_t)(p7 & 0xFFFF) * 512 + (p7 >> 16) * DIM + l2);
        ax += __uint_as_float(u0 << 16); ay += __uint_as_float(u0 & 0xFFFF0000u);
        ax += __uint_as_float(u1 << 16); ay += __uint_as_float(u1 & 0xFFFF0000u);
        ax += __uint_as_float(u2 << 16); ay += __uint_as_float(u2 & 0xFFFF0000u);
        ax += __uint_as_float(u3 << 16); ay += __uint_as_float(u3 & 0xFFFF0000u);
        ax += __uint_as_float(u4 << 16); ay += __uint_as_float(u4 & 0xFFFF0000u);
        ax += __uint_as_float(u5 << 16); ay += __uint_as_float(u5 & 0xFFFF0000u);
        ax += __uint_as_float(u6 << 16); ay += __uint_as_float(u6 & 0xFFFF0000u);
        ax += __uint_as_float(u7 << 16); ay += __uint_as_float(u7 & 0xFFFF0000u);
    }
    for (; i < end; ++i) {
        const int p = perm[i];
        const unsigned int u = *(const unsigned int*)(Ybf + (size_t)(p & 0xFFFF) * 512 + (p >> 16) * DIM + l2);
        ax += __uint_as_float(u << 16);
        ay += __uint_as_float(u & 0xFFFF0000u);
    }
    const unsigned int bx = (unsigned short)f2bf(ax);
    const unsigned int by = (unsigned short)f2bf(ay);
    *(unsigned int*)(ah + (size_t)node * 256 + l2) = (by << 16) | bx;
}

// ---------------------------------------------------------------------------
// GRU gates from fused g[v][512] = (r_sum, z_sum, inn, hn).
// h' = (1-z)*n + z*h; writes fp32 h_out and bf16 h into ah[:,128:256].
// ---------------------------------------------------------------------------
__device__ __forceinline__ float sigf(float x) { return 1.f / (1.f + expf(-x)); }

__global__ __launch_bounds__(256)
void gru_gate(const float* __restrict__ g, const float* __restrict__ h_in,
              float* __restrict__ h_out, unsigned short* __restrict__ ah) {
    const int idx = blockIdx.x * 256 + threadIdx.x;
    const int v = idx >> 5;
    const int q = (idx & 31) << 2;
    if (v >= NNODES) return;
    const size_t gb = (size_t)v * 512 + q;
    const float4 rs = *(const float4*)(g + gb);
    const float4 zs = *(const float4*)(g + gb + 128);
    const float4 in4 = *(const float4*)(g + gb + 256);
    const float4 hn = *(const float4*)(g + gb + 384);
    const float4 h4 = *(const float4*)(h_in + (size_t)v * DIM + q);
    float4 o;
    {
        const float r = sigf(rs.x), z = sigf(zs.x);
        const float n = tanhf(in4.x + r * hn.x);
        o.x = (1.f - z) * n + z * h4.x;
    }
    {
        const float r = sigf(rs.y), z = sigf(zs.y);
        const float n = tanhf(in4.y + r * hn.y);
        o.y = (1.f - z) * n + z * h4.y;
    }
    {
        const float r = sigf(rs.z), z = sigf(zs.z);
        const float n = tanhf(in4.z + r * hn.z);
        o.z = (1.f - z) * n + z * h4.z;
    }
    {
        const float r = sigf(rs.w), z = sigf(zs.w);
        const float n = tanhf(in4.w + r * hn.w);
        o.w = (1.f - z) * n + z * h4.w;
    }
    *(float4*)(h_out + (size_t)v * DIM + q) = o;
    ushort4 ob;
    ob.x = (unsigned short)f2bf(o.x); ob.y = (unsigned short)f2bf(o.y);
    ob.z = (unsigned short)f2bf(o.z); ob.w = (unsigned short)f2bf(o.w);
    *(ushort4*)(ah + (size_t)v * 256 + 128 + q) = ob;
}

// ---------------------------------------------------------------------------
extern "C" void kernel_launch(void* const* d_in, const int* in_sizes, int n_in,
                              void* d_out, int out_size, void* d_ws, size_t ws_size,
                              hipStream_t stream) {
    const float* feat  = (const float*)d_in[0];
    const float* W_lin = (const float*)d_in[1];   // [512,128]
    const float* b_lin = (const float*)d_in[2];   // [512]
    const float* w_ih  = (const float*)d_in[3];   // [384,128]
    const float* w_hh  = (const float*)d_in[4];   // [384,128]
    const float* b_ih  = (const float*)d_in[5];   // [384]
    const float* b_hh  = (const float*)d_in[6];   // [384]
    const int*   src   = (const int*)d_in[7];
    const int*   dst   = (const int*)d_in[8];
    const int*   et    = (const int*)d_in[9];
    float* out = (float*)d_out;

    // ws layout (float units):
    //   h    : [0, 6.4M) fp32
    //   Yg   : [6.4M, 32M): Y bf16 (12.8M floats) overlaid by g fp32 (25.6M);
    //          Y dead before fused GEMM writes g.
    //   ah   : bf16 [50000][256] at [32M, 38.4M)   (= NNODES*128 floats)
    //   ints at 38.4M: row_start[50001], perm[800000], partial[98], bloff[98]
    //   weights after ints: wlin_swz 65536 us, wbig_swz 131072 us, bias_big 512 f
    //   cnt/cursor transient over Yg region (dead during CSR build)
    float* h  = (float*)d_ws;
    float* Yg = h + (size_t)NNODES * DIM;                 // 6.4M
    unsigned short* Y = (unsigned short*)Yg;
    float* g  = Yg;
    unsigned short* ah = (unsigned short*)(Yg + (size_t)NNODES * 512);  // 32M
    int* row_start = (int*)((float*)ah + (size_t)NNODES * 128);         // 38.4M (FIX: was *64)
    int* perm      = row_start + (NNODES + 1);
    int* partial   = perm + NEDGES;
    int* bloff     = partial + NB_SCAN;
    unsigned short* wlin_swz = (unsigned short*)(((uintptr_t)(bloff + NB_SCAN) + 15) & ~(uintptr_t)15);
    unsigned short* wbig_swz = wlin_swz + 65536;
    float* bias_big = (float*)(wbig_swz + 131072);
    int* cnt    = (int*)Yg;
    int* cursor = cnt + NNODES + 64;

    const dim3 blk(256);
    const int mblocks = (NNODES + 127) / 128;   // 391
    const int eblocks = (NEDGES + 255) / 256;   // 3125

    // ---- one-time: weight prep, feat->bf16, dst-CSR build ----
    conv_swz_w<<<dim3(32), blk, 0, stream>>>(W_lin, wlin_swz, 8192);
    conv_swz_wbig<<<dim3(64), blk, 0, stream>>>(w_ih, w_hh, wbig_swz);
    build_bias_big<<<dim3(2), blk, 0, stream>>>(b_ih, b_hh, bias_big);
    feat2bf<<<dim3((NNODES * 32 + 255) / 256), blk, 0, stream>>>(feat, ah);
    hipMemsetAsync(cnt, 0, (size_t)NNODES * sizeof(int), stream);
    hist_dst<<<dim3(eblocks), blk, 0, stream>>>(dst, cnt);
    scan_blksum<<<dim3(NB_SCAN), blk, 0, stream>>>(cnt, partial);
    scan_partials<<<dim3(1), dim3(128), 0, stream>>>(partial, bloff);
    scan_final<<<dim3(NB_SCAN), blk, 0, stream>>>(cnt, bloff, row_start, cursor);
    scatter_edges<<<dim3(eblocks), blk, 0, stream>>>(src, dst, et, cursor, perm);

    for (int s = 0; s < 3; ++s) {
        const float* h_in = (s == 0) ? feat : h;
        float* h_out = (s == 2) ? out : h;

        // Y(bf16) = h_bf @ W_lin^T + b_lin   [50000, 512]; A = ah[:,128:256]
        gemm_mfma_bias<1, unsigned short><<<dim3(mblocks, 4), blk, 0, stream>>>(
            ah + 128, 256, wlin_swz, b_lin, Y, NNODES, 512);
        // ah[:,0:128] = sum_{e: dst=v} Y[src_e, et_e*128..]
        edge_agg<<<dim3((NNODES + 3) / 4), blk, 0, stream>>>(Y, perm, row_start, ah);
        // g = [a|h] @ W_big^T + bias_big   [50000, 512], K=256
        gemm_mfma_bias<2, float><<<dim3(mblocks, 4), blk, 0, stream>>>(
            ah, 256, wbig_swz, bias_big, g, NNODES, 512);
        // gates (also refreshes bf16 h in ah for next step)
        gru_gate<<<dim3((NNODES * 32 + 255) / 256), blk, 0, stream>>>(g, h_in, h_out, ah);
    }
}